// Round 9
// baseline (163.314 us; speedup 1.0000x reference)
//
#include <hip/hip_runtime.h>

#define BATCH 32
#define NOBJ  64
#define PADK  264   // halfs; A-tile row stride 528 B (16B-aligned)

typedef _Float16 f16x2 __attribute__((ext_vector_type(2)));
typedef _Float16 f16x4 __attribute__((ext_vector_type(4)));
typedef _Float16 f16x8 __attribute__((ext_vector_type(8)));
typedef float    f32x4 __attribute__((ext_vector_type(4)));
typedef float    f32x16 __attribute__((ext_vector_type(16)));

#define MFMA32(a, b, c) __builtin_amdgcn_mfma_f32_32x32x16_f16((a), (b), (c), 0, 0, 0)

// ---------------------------------------------------------------------------
// Layer-0 split: pair = [x_j-part (65) | x_i-part (129)].
// x_i-part is constant over the 64 j-rows -> precompute
//   ci[b][i][n] = sum_q x_aux[b][i][q] * g1w[65+q][n] + i * g1w[193][n]  (fp32)
// and run layer-0 MFMA with K=80 (real 65: x_j feats + coord j),
// acc initialized from ci.  Exact same arithmetic as the full K=194 GEMM.
//
// Activation LDS layout (layers >= 1): physical col p = 64*nq + 2*c + ns
// holds logical col n = 64*nq + 32*ns + c. Epilogue writes f16x2.
// Next layer's weight k-order: klog(p) = 64*(p>>6) + 32*(p&1) + ((p&63)>>1).
// ---------------------------------------------------------------------------

// ---------------------------------------------------------------------------
// Kernel 0a: per-(b,i) layer-0 constant ci (fp32). 512 blocks x 256 thr;
// block -> (b, group of 4 i). Thread t owns output col n = t.
// ---------------------------------------------------------------------------
__global__ __launch_bounds__(256) void precompute_ci(
    const float* __restrict__ x_aux, const float* __restrict__ g1w,
    float* __restrict__ ci) {
  __shared__ float xs[4][128];
  const int blk = blockIdx.x;          // 512 = 32 b x 16 groups
  const int b  = blk >> 4;
  const int i0 = (blk & 15) * 4;
  const int t  = threadIdx.x;

#pragma unroll
  for (int u = 0; u < 2; ++u) {
    int idx = u * 256 + t;             // 0..511
    int j = idx >> 7, k = idx & 127;
    xs[j][k] = x_aux[((size_t)(b * NOBJ + i0 + j)) * 128 + k];
  }
  __syncthreads();

  float c0 = 0.f, c1 = 0.f, c2 = 0.f, c3 = 0.f;
#pragma unroll 8
  for (int k = 0; k < 128; ++k) {
    float w = g1w[(size_t)(65 + k) * 256 + t];
    c0 += xs[0][k] * w; c1 += xs[1][k] * w;
    c2 += xs[2][k] * w; c3 += xs[3][k] * w;
  }
  float wc = g1w[(size_t)193 * 256 + t];
  c0 += (float)(i0 + 0) * wc;
  c1 += (float)(i0 + 1) * wc;
  c2 += (float)(i0 + 2) * wc;
  c3 += (float)(i0 + 3) * wc;
  ci[((size_t)(b * NOBJ + i0 + 0)) * 256 + t] = c0;
  ci[((size_t)(b * NOBJ + i0 + 1)) * 256 + t] = c1;
  ci[((size_t)(b * NOBJ + i0 + 2)) * 256 + t] = c2;
  ci[((size_t)(b * NOBJ + i0 + 3)) * 256 + t] = c3;
}

// ---------------------------------------------------------------------------
// Kernel 0b: repack g-weights to f16 in MFMA B-FRAGMENT order:
//   wtf[l][ngrp=8][kk=16][lane=64][j=8] = W_l[klog][nlog]
//   nlog = ngrp*32 + (lane&31), kphys = kk*16 + (lane>>5)*8 + j
//   l==0 (K=80 used): klog = kp for kp<64 (x_j feats), 64 -> 64 (coord j),
//                     else zero (x_i part lives in ci).
//   l>=1: klog = 64*(kp>>6) + 32*(kp&1) + ((kp&63)>>1)  (2-col interleave).
// Grid: 32 blocks (l=blk>>3, ngrp=blk&7) x 256 threads. Also zeroes xg.
// ---------------------------------------------------------------------------
__global__ __launch_bounds__(256) void prep_weights(
    const float* __restrict__ g1w, const float* __restrict__ g2w,
    const float* __restrict__ g3w, const float* __restrict__ g4w,
    _Float16* __restrict__ wtf, float* __restrict__ xg) {
  __shared__ _Float16 tile[256][33];   // [kphys][n-local]
  const int blk = blockIdx.x;
  const int t = threadIdx.x;
  xg[blk * 256 + t] = 0.0f;            // 32 blocks x 256 = full 8192 floats

  const int l  = blk >> 3;
  const int nt = blk & 7;
  const float* src = (l == 0) ? g1w : (l == 1) ? g2w : (l == 2) ? g3w : g4w;

  const int nn = t & 31, kb = t >> 5;   // 8 kphys-rows per pass
#pragma unroll 4
  for (int pass = 0; pass < 32; ++pass) {
    int kp = pass * 8 + kb;             // physical k
    int kl;                             // logical k in W_l
    if (l == 0) {
      kl = (kp <= 64) ? kp : -1;        // 0..63 feats, 64 coord-j, rest zero
    } else {
      kl = 64 * (kp >> 6) + 32 * (kp & 1) + ((kp & 63) >> 1);
    }
    float v = (kl >= 0) ? src[(size_t)kl * 256 + nt * 32 + nn] : 0.0f;
    tile[kp][nn] = (_Float16)v;
  }
  __syncthreads();

  const int lane = t & 63;
  const int nfrag = lane & 31;
  const int kbase = (lane >> 5) * 8;
  _Float16* dst = wtf + ((size_t)(l * 8 + nt) * 16) * 512;
#pragma unroll
  for (int q = 0; q < 4; ++q) {
    int kk = (t >> 6) + 4 * q;
    f16x8 fr;
#pragma unroll
    for (int j = 0; j < 8; ++j)
      fr[j] = tile[kk * 16 + kbase + j][nfrag];
    *(f16x8*)(dst + (size_t)kk * 512 + lane * 8) = fr;
  }
}

// ---------------------------------------------------------------------------
// One layer GEMM for a wave: Mt=4 M-tiles x Nt=2 N-groups, STEPS k-steps.
// Whole-layer B preloaded into registers. acc[idx = m*2 + ns].
// ---------------------------------------------------------------------------
template <int STEPS>
__device__ __forceinline__ void do_layer(
    const _Float16* __restrict__ bp0, const _Float16* __restrict__ bp1,
    const _Float16* __restrict__ arow, f32x16 acc[8]) {
  f16x8 b0[STEPS], b1[STEPS];
#pragma unroll
  for (int kk = 0; kk < STEPS; ++kk) {
    b0[kk] = *(const f16x8*)(bp0 + kk * 512);
    b1[kk] = *(const f16x8*)(bp1 + kk * 512);
  }
#pragma unroll
  for (int kk = 0; kk < STEPS; ++kk) {
#pragma unroll
    for (int m = 0; m < 4; ++m) {
      f16x8 a = *(const f16x8*)(arow + (size_t)m * 32 * PADK + kk * 16);
      acc[m * 2]     = MFMA32(a, b0[kk], acc[m * 2]);
      acc[m * 2 + 1] = MFMA32(a, b1[kk], acc[m * 2 + 1]);
    }
  }
}

// ---------------------------------------------------------------------------
// Kernel 1: fused g-MLP (4 layers) + sum-pool for TWO i's per block.
// Block = 256 thr (4 waves). M=128 (2 i's x 64 j), N=256.
// Wave w = nq: Mt=4 (all 128 rows) x Nt=2 (N-groups 2nq, 2nq+1); dup=1 B.
// Layer 0: K=80 (5 steps), acc init from ci. Layers 1-3: K=256 (16 steps).
// Epilogue: f16x2 packed writes via 2-col interleaved activation layout.
// ---------------------------------------------------------------------------
__global__ __launch_bounds__(256, 2) void g_mlp_pool(
    const float* __restrict__ x_aux,          // [B, 64, 128] fp32
    const _Float16* __restrict__ wtf,         // fragment-ordered, 512 KB
    const float* __restrict__ ci,             // [B*64][256] fp32
    const float* __restrict__ g1b, const float* __restrict__ g2b,
    const float* __restrict__ g3b, const float* __restrict__ g4b,
    float* __restrict__ xg) {                 // [B][256] fp32 (pre-zeroed)
  __shared__ _Float16 As[128][PADK];          // 67.6 KB -> 2 blocks/CU

  const int b  = blockIdx.x >> 5;
  const int i0 = (blockIdx.x & 31) * 2;
  const int t  = threadIdx.x;

  // ---- build layer-0 input tile: only the x_j-part (cols 0..79) ----
  {
    const float* xb = x_aux + (size_t)b * NOBJ * 128;
    const int c4 = t & 15, r0 = t >> 4;       // cols [0,64): 16 rows/pass
#pragma unroll
    for (int it = 0; it < 8; ++it) {
      int r = it * 16 + r0;
      f32x4 v = *(const f32x4*)(xb + (size_t)(r & 63) * 128 + c4 * 4);
      f16x4 hh = {(_Float16)v[0], (_Float16)v[1], (_Float16)v[2], (_Float16)v[3]};
      *(f16x4*)&As[r][c4 * 4] = hh;
    }
    if (t < 128) {                            // cols [64,80): coord j + zeros
      f16x8 z1 = {};
      z1[0] = (_Float16)(t & 63);             // coord j
      *(f16x8*)&As[t][64] = z1;
      f16x8 z = {};
      *(f16x8*)&As[t][72] = z;
    }
  }
  __syncthreads();

  const int lane = t & 63;
  const int nq   = t >> 6;          // 0..3 -> N-pair (groups 2nq, 2nq+1)
  const int c31  = lane & 31;
  const int h    = lane >> 5;       // 0/1
  const int n0   = nq * 64;
  const float* gb[4] = {g1b, g2b, g3b, g4b};

  // per-lane layer-0 constants (broadcast over the 16 rows of each acc reg)
  const float* cb = ci + (size_t)(b * NOBJ + i0) * 256;
  const float ci_v[2][2] = {{cb[n0 + c31], cb[n0 + 32 + c31]},
                            {cb[256 + n0 + c31], cb[256 + 32 + n0 + c31]}};

  for (int layer = 0; layer < 4; ++layer) {
    const float bv0 = gb[layer][n0 + c31];
    const float bv1 = gb[layer][n0 + 32 + c31];

    f32x16 acc[8];   // [m*2 + ns]

    const _Float16* bp0 =
        wtf + ((size_t)(layer * 8 + nq * 2) * 16) * 512 + lane * 8;
    const _Float16* bp1 = bp0 + 16 * 512;
    const _Float16* arow = &As[c31][h * 8];

    if (layer == 0) {
      // rows 0..63 (m=0,1) belong to i0; rows 64..127 (m=2,3) to i0+1
#pragma unroll
      for (int m = 0; m < 4; ++m)
#pragma unroll
        for (int ns = 0; ns < 2; ++ns)
#pragma unroll
          for (int reg = 0; reg < 16; ++reg)
            acc[m * 2 + ns][reg] = ci_v[m >> 1][ns];
      do_layer<5>(bp0, bp1, arow, acc);
    } else {
#pragma unroll
      for (int x = 0; x < 8; ++x) acc[x] = (f32x16){};
      do_layer<16>(bp0, bp1, arow, acc);
    }

    if (layer < 3) {
      __syncthreads();   // all waves done reading As
      // C/D layout: col = lane&31, row = (reg&3) + 8*(reg>>2) + 4*h.
      // Pack both N-streams as f16x2 at phys col 64*nq + 2*c.
#pragma unroll
      for (int m = 0; m < 4; ++m)
#pragma unroll
        for (int g = 0; g < 4; ++g)
#pragma unroll
          for (int r = 0; r < 4; ++r) {
            const int row = m * 32 + g * 8 + h * 4 + r;
            const int reg = g * 4 + r;
            f16x2 pk = {(_Float16)fmaxf(acc[m * 2][reg] + bv0, 0.f),
                        (_Float16)fmaxf(acc[m * 2 + 1][reg] + bv1, 0.f)};
            *(f16x2*)&As[row][n0 + 2 * c31] = pk;
          }
      __syncthreads();
    } else {
      // layer 4: bias + relu + pool over all 128 rows (both i's)
      float s0 = 0.f, s1 = 0.f;
#pragma unroll
      for (int m = 0; m < 4; ++m)
#pragma unroll
        for (int reg = 0; reg < 16; ++reg) {
          s0 += fmaxf(acc[m * 2][reg] + bv0, 0.f);
          s1 += fmaxf(acc[m * 2 + 1][reg] + bv1, 0.f);
        }
      s0 += __shfl_xor(s0, 32, 64);   // combine h=0/h=1 row halves
      s1 += __shfl_xor(s1, 32, 64);
      if (h == 0) {
        atomicAdd(&xg[b * 256 + n0 + c31], s0);
        atomicAdd(&xg[b * 256 + n0 + 32 + c31], s1);
      }
    }
  }
}

// ---------------------------------------------------------------------------
// Kernel 2: f-MLP. One block per batch, 1024 threads: n = t&255 owns column,
// kc = t>>8 owns a 64-wide k-chunk; LDS reduce the 4 partials per column.
// ---------------------------------------------------------------------------
__global__ __launch_bounds__(1024) void f_mlp(
    const float* __restrict__ xg,
    const float* __restrict__ f1w, const float* __restrict__ f1b,
    const float* __restrict__ f2w, const float* __restrict__ f2b,
    const float* __restrict__ f3w, const float* __restrict__ f3b,
    float* __restrict__ out) {
  __shared__ float xs[256], ys[256], ps[4][256];
  const int b = blockIdx.x;
  const int t = threadIdx.x;
  const int n = t & 255;
  const int kc = t >> 8;

  if (t < 256) xs[t] = xg[b * 256 + t];
  __syncthreads();

  float p = 0.f;
#pragma unroll 8
  for (int k0 = 0; k0 < 64; ++k0) {
    int k = kc * 64 + k0;
    p += xs[k] * f1w[k * 256 + n];
  }
  ps[kc][n] = p;
  __syncthreads();
  if (t < 256)
    ys[t] = fmaxf(f1b[t] + ps[0][t] + ps[1][t] + ps[2][t] + ps[3][t], 0.f);
  __syncthreads();

  p = 0.f;
#pragma unroll 8
  for (int k0 = 0; k0 < 64; ++k0) {
    int k = kc * 64 + k0;
    p += ys[k] * f2w[k * 256 + n];
  }
  ps[kc][n] = p;
  __syncthreads();
  if (t < 256)
    xs[t] = fmaxf(f2b[t] + ps[0][t] + ps[1][t] + ps[2][t] + ps[3][t], 0.f);
  __syncthreads();

  p = 0.f;
#pragma unroll 8
  for (int k0 = 0; k0 < 64; ++k0) {
    int k = kc * 64 + k0;
    p += xs[k] * f3w[k * 256 + n];
  }
  ps[kc][n] = p;
  __syncthreads();
  if (t < 256)
    out[b * 256 + t] = f3b[t] + ps[0][t] + ps[1][t] + ps[2][t] + ps[3][t];
}

// ---------------------------------------------------------------------------
extern "C" void kernel_launch(void* const* d_in, const int* in_sizes, int n_in,
                              void* d_out, int out_size, void* d_ws, size_t ws_size,
                              hipStream_t stream) {
  const float* x_aux = (const float*)d_in[0];
  const float* g1w = (const float*)d_in[1];
  const float* g1b = (const float*)d_in[2];
  const float* g2w = (const float*)d_in[3];
  const float* g2b = (const float*)d_in[4];
  const float* g3w = (const float*)d_in[5];
  const float* g3b = (const float*)d_in[6];
  const float* g4w = (const float*)d_in[7];
  const float* g4b = (const float*)d_in[8];
  const float* f1w = (const float*)d_in[9];
  const float* f1b = (const float*)d_in[10];
  const float* f2w = (const float*)d_in[11];
  const float* f2b = (const float*)d_in[12];
  const float* f3w = (const float*)d_in[13];
  const float* f3b = (const float*)d_in[14];
  float* out = (float*)d_out;

  _Float16* wtf = (_Float16*)d_ws;                                  // 512 KB
  float* xg = (float*)((char*)d_ws + 512u * 1024u);                 // 32 KB
  float* ci = (float*)((char*)d_ws + 512u * 1024u + 32u * 1024u);   // 2 MB

  hipLaunchKernelGGL(precompute_ci, dim3(512), dim3(256), 0, stream,
                     x_aux, g1w, ci);
  hipLaunchKernelGGL(prep_weights, dim3(32), dim3(256), 0, stream,
                     g1w, g2w, g3w, g4w, wtf, xg);
  hipLaunchKernelGGL(g_mlp_pool, dim3(BATCH * 32), dim3(256), 0, stream,
                     x_aux, wtf, ci, g1b, g2b, g3b, g4b, xg);
  hipLaunchKernelGGL(f_mlp, dim3(BATCH), dim3(1024), 0, stream,
                     xg, f1w, f1b, f2w, f2b, f3w, f3b, out);
}